// Round 4
// baseline (155.378 us; speedup 1.0000x reference)
//
#include <hip/hip_runtime.h>
#include <math.h>
#include <stdint.h>

#define NM 8          // nmul
#define NPAR 12
#define PFD 4         // prefetch depth in timesteps (rolling register buffer)

__global__ __launch_bounds__(64, 1) void hbv_kernel(
    const float* __restrict__ x,      // [T, G, 3]  (prcp, tmean, pet)
    const float* __restrict__ praw,   // [1, G, 12, NM] in [0,1)
    float* __restrict__ out,          // [T, G, NM]
    int G, int T)
{
    const int tid = blockIdx.x * blockDim.x + threadIdx.x;
    const int npair = G * (NM / 2);          // 2 chains (m, m+1) per thread
    if (tid >= npair) return;
    const int g  = tid >> 2;                 // / (NM/2)
    const int mp = (tid & 3) << 1;           // m0 = 0,2,4,6

    // Parameter bounds: BETA, FC, K0, K1, K2, LP, PERC, UZL, TT, CFMAX, CFR, CWH
    const float lb[NPAR] = {1.0f, 50.0f, 0.05f, 0.01f, 0.001f, 0.2f, 0.0f, 0.0f, -2.5f, 0.5f, 0.0f, 0.0f};
    const float ub[NPAR] = {6.0f, 1000.0f, 0.9f, 0.5f, 0.2f, 1.0f, 10.0f, 100.0f, 2.5f, 10.0f, 0.1f, 0.2f};

    // Two independent chains per lane: A = m0, B = m0+1 (hand-duplicated scalars)
    float pA[NPAR], pB[NPAR];
    const float* pr = praw + (size_t)g * (NPAR * NM) + mp;
    #pragma unroll
    for (int i = 0; i < NPAR; ++i) {
        const float s = ub[i] - lb[i];
        pA[i] = pr[i * NM]     * s + lb[i];   // adjacent dwords -> dwordx2 load
        pB[i] = pr[i * NM + 1] * s + lb[i];
    }

    const float BETAA = pA[0], FCA = pA[1], K0A = pA[2], K1A = pA[3], K2A = pA[4], LPA = pA[5],
                PERCcA = pA[6], UZLA = pA[7], TTA = pA[8], CFMAXA = pA[9], CFRA = pA[10], CWHA = pA[11];
    const float BETAB = pB[0], FCB = pB[1], K0B = pB[2], K1B = pB[3], K2B = pB[4], LPB = pB[5],
                PERCcB = pB[6], UZLB = pB[7], TTB = pB[8], CFMAXB = pB[9], CFRB = pB[10], CWHB = pB[11];

    const float invFCA       = 1.0f / FCA;             const float invFCB       = 1.0f / FCB;
    const float invLPFCA     = 1.0f / (LPA * FCA);     const float invLPFCB     = 1.0f / (LPB * FCB);
    const float CFMAX_TTA    = CFMAXA * TTA;           const float CFMAX_TTB    = CFMAXB * TTB;
    const float CFRCFMAXA    = CFRA * CFMAXA;          const float CFRCFMAXB    = CFRB * CFMAXB;
    const float CFRCFMAX_TTA = CFRCFMAXA * TTA;        const float CFRCFMAX_TTB = CFRCFMAXB * TTB;
    const float OMK1A        = 1.0f - K1A;             const float OMK1B        = 1.0f - K1B;
    const float OMK2A        = 1.0f - K2A;             const float OMK2B        = 1.0f - K2B;

    float SPa = 0.001f, MWa = 0.001f, SMa = 0.001f, SUZa = 0.001f, SLZa = 0.001f;
    float SPb = 0.001f, MWb = 0.001f, SMb = 0.001f, SUZb = 0.001f, SLZb = 0.001f;

    // 32-bit byte offsets from uniform (SGPR) bases -> saddr-form loads/stores
    const char* xb = (const char*)x;
    char* ob = (char*)out;
    const uint32_t xstep = (uint32_t)G * 12u;                 // bytes per timestep in x
    uint32_t poff = (uint32_t)g * 12u;
    const uint32_t xmax  = poff + (uint32_t)(T - 1) * xstep;  // clamp target (last valid row)
    uint32_t ooff = (uint32_t)(g * NM + mp) * 4u;             // 8B-aligned (mp even)
    const uint32_t ostep = (uint32_t)(G * NM) * 4u;

    // --- rolling forcing buffer; state-independent precompute hoisted (per chain) ---
    float RbA[PFD], SbA[PFD], MCA[PFD], RCA[PFD];
    float RbB[PFD], SbB[PFD], MCB[PFD], RCB[PFD];
    float Eb[PFD];

    #define REFILL(d)                                                          \
    {                                                                          \
        const float* a_ = (const float*)(xb + poff);                           \
        const float P_  = a_[0];   /* adjacent dwords -> global_load_dwordx3 */\
        const float Tt_ = a_[1];                                               \
        Eb[d]           = a_[2];                                               \
        const float rA_ = (Tt_ >= TTA) ? P_ : 0.0f;                            \
        const float rB_ = (Tt_ >= TTB) ? P_ : 0.0f;                            \
        RbA[d] = rA_;  SbA[d] = P_ - rA_;                                      \
        RbB[d] = rB_;  SbB[d] = P_ - rB_;                                      \
        MCA[d] = fmaxf(fmaf(CFMAXA, Tt_, -CFMAX_TTA), 0.0f);                   \
        MCB[d] = fmaxf(fmaf(CFMAXB, Tt_, -CFMAX_TTB), 0.0f);                   \
        RCA[d] = fmaxf(fmaf(-CFRCFMAXA, Tt_, CFRCFMAX_TTA), 0.0f);             \
        RCB[d] = fmaxf(fmaf(-CFRCFMAXB, Tt_, CFRCFMAX_TTB), 0.0f);             \
        const uint32_t nx_ = poff + xstep;                                     \
        poff = (nx_ < xmax) ? nx_ : xmax;                                      \
    }

    #pragma unroll
    for (int d = 0; d < PFD; ++d) REFILL(d)

    // Interleaved A/B step: B's independent ops fill A's dependency-stall slots.
    auto step2 = [&](float RA, float RB, float SA, float SB,
                     float mcA, float mcB, float rcA, float rcB, float PET) -> float2 {
        // --- snow routine ---
        SPa += SA;                                   SPb += SB;
        const float meltA = fminf(mcA, SPa);         const float meltB = fminf(mcB, SPb);
        MWa += meltA;                                MWb += meltB;
        SPa -= meltA;                                SPb -= meltB;
        const float refrA = fminf(rcA, MWa);         const float refrB = fminf(rcB, MWb);
        SPa += refrA;                                SPb += refrB;
        MWa -= refrA;                                MWb -= refrB;
        const float cwA = CWHA * SPa;                const float cwB = CWHB * SPb;
        const float tsA = fmaxf(MWa - cwA, 0.0f);    const float tsB = fmaxf(MWb - cwB, 0.0f);
        MWa = fminf(MWa, cwA);                       MWb = fminf(MWb, cwB);

        // --- soil routine ---
        const float lgA = __builtin_amdgcn_logf(SMa * invFCA);
        const float lgB = __builtin_amdgcn_logf(SMb * invFCB);
        const float blA = fminf(BETAA * lgA, 0.0f);  const float blB = fminf(BETAB * lgB, 0.0f);
        const float swA = __builtin_amdgcn_exp2f(blA);
        const float swB = __builtin_amdgcn_exp2f(blB);
        const float rtA = RA + tsA;                  const float rtB = RB + tsB;
        const float rgA = rtA * swA;                 const float rgB = rtB * swB;
        SMa = SMa + rtA - rgA;                       SMb = SMb + rtB - rgB;
        const float exA = fmaxf(SMa - FCA, 0.0f);    const float exB = fmaxf(SMb - FCB, 0.0f);
        SMa = fminf(SMa, FCA);                       SMb = fminf(SMb, FCB);
        const float etA = fminf(fminf(SMa, SMa * invLPFCA * PET), PET);
        const float etB = fminf(fminf(SMb, SMb * invLPFCB * PET), PET);
        SMa = fmaxf(SMa - etA, 1e-5f);               SMb = fmaxf(SMb - etB, 1e-5f);

        // --- response routine (Q0+Q1 == SUZ2 - SUZ4) ---
        SUZa = SUZa + rgA + exA;                     SUZb = SUZb + rgB + exB;
        const float pcA = fminf(SUZa, PERCcA);       const float pcB = fminf(SUZb, PERCcB);
        const float s2A = fmaxf(SUZa - PERCcA, 0.0f);const float s2B = fmaxf(SUZb - PERCcB, 0.0f);
        const float s3A = fminf(s2A, fmaf(-K0A, s2A - UZLA, s2A));
        const float s3B = fminf(s2B, fmaf(-K0B, s2B - UZLB, s2B));
        const float s4A = s3A * OMK1A;               const float s4B = s3B * OMK1B;
        SUZa = s4A;                                  SUZb = s4B;
        const float slA = SLZa + pcA;                const float slB = SLZb + pcB;
        const float q2A = K2A * slA;                 const float q2B = K2B * slB;
        SLZa = slA * OMK2A;                          SLZb = slB * OMK2B;
        float2 q; q.x = (s2A - s4A) + q2A;           q.y = (s2B - s4B) + q2B;
        return q;
    };

    // --- main loop: unguarded, unrolled by PFD; consume slot d then refill for t+PFD ---
    int tb = 0;
    for (; tb + PFD <= T; tb += PFD) {
        #pragma unroll
        for (int d = 0; d < PFD; ++d) {
            const float RA = RbA[d], RB = RbB[d], SA = SbA[d], SB = SbB[d];
            const float mA = MCA[d], mB = MCB[d], rA = RCA[d], rB = RCB[d];
            const float E  = Eb[d];
            REFILL(d)                        // loads issue before the dependent step math
            const float2 q = step2(RA, RB, SA, SB, mA, mB, rA, rB, E);
            *(float2*)(ob + ooff) = q;       // one dwordx2 store, coalesced across the wave
            ooff += ostep;
        }
    }
    // --- tail: 0..PFD-1 guarded steps, static slot indices ---
    #pragma unroll
    for (int d = 0; d < PFD; ++d) {
        if (tb + d < T) {
            const float2 q = step2(RbA[d], RbB[d], SbA[d], SbB[d],
                                   MCA[d], MCB[d], RCA[d], RCB[d], Eb[d]);
            *(float2*)(ob + ooff) = q;
            ooff += ostep;
        }
    }
    #undef REFILL
}

extern "C" void kernel_launch(void* const* d_in, const int* in_sizes, int n_in,
                              void* d_out, int out_size, void* d_ws, size_t ws_size,
                              hipStream_t stream) {
    const float* x    = (const float*)d_in[0];   // [T, G, 3]
    const float* praw = (const float*)d_in[1];   // [1, G, 12, 8]
    float* out = (float*)d_out;                  // [T, G, 8]

    const int G = in_sizes[1] / (NPAR * NM);     // 4000
    const int T = in_sizes[0] / (3 * G);         // 730

    const int npair = G * (NM / 2);              // 16000 threads, 2 chains each
    const int block = 64;
    const int grid = (npair + block - 1) / block;
    hbv_kernel<<<grid, block, 0, stream>>>(x, praw, out, G, T);
}

// Round 5
// 114.383 us; speedup vs baseline: 1.3584x; 1.3584x over previous
//
#include <hip/hip_runtime.h>
#include <math.h>
#include <stdint.h>

#define NM 8          // nmul
#define NPAR 12
#define PFD 4         // prefetch depth in timesteps (rolling register buffer)

__global__ __launch_bounds__(64, 1) void hbv_kernel(
    const float* __restrict__ x,      // [T, G, 3]  (prcp, tmean, pet)
    const float* __restrict__ praw,   // [1, G, 12, NM] in [0,1)
    float* __restrict__ out,          // [T, G, NM]
    int G, int T)
{
    const int tid = blockIdx.x * blockDim.x + threadIdx.x;
    const int total = G * NM;                // 1 chain per lane
    if (tid >= total) return;
    const int g = tid >> 3;                  // / NM
    const int m = tid & 7;                   // % NM

    // Parameter bounds: BETA, FC, K0, K1, K2, LP, PERC, UZL, TT, CFMAX, CFR, CWH
    const float lb[NPAR] = {1.0f, 50.0f, 0.05f, 0.01f, 0.001f, 0.2f, 0.0f, 0.0f, -2.5f, 0.5f, 0.0f, 0.0f};
    const float ub[NPAR] = {6.0f, 1000.0f, 0.9f, 0.5f, 0.2f, 1.0f, 10.0f, 100.0f, 2.5f, 10.0f, 0.1f, 0.2f};

    float p[NPAR];
    const float* pr = praw + (size_t)g * (NPAR * NM) + m;
    #pragma unroll
    for (int i = 0; i < NPAR; ++i) p[i] = pr[i * NM] * (ub[i] - lb[i]) + lb[i];

    float BETA = p[0], FC = p[1];
    const float K0 = p[2], K1 = p[3];
    float K2 = p[4];
    const float LP = p[5];
    float PERCc = p[6];
    const float UZL = p[7];
    float TT = p[8], CFMAX = p[9];
    const float CFR = p[10];
    float CWH = p[11];

    // --- derived loop-invariants (all folded for fma forms) ---
    float invLPFC     = 1.0f / (LP * FC);
    float nCFMAX_TT   = -(CFMAX * TT);
    float nCFRCFMAX   = -(CFR * CFMAX);
    float CFRCFMAX_TT = (CFR * CFMAX) * TT;
    float nBLFC       = -BETA * __builtin_amdgcn_logf(FC);   // -BETA*log2(FC)
    float OMK0        = 1.0f - K0;
    float K0UZL       = K0 * UZL;
    float OMK1        = 1.0f - K1;
    float OMK2        = 1.0f - K2;

    // Pin every per-step invariant into a VGPR: opaque def stops the register
    // allocator from shedding these live ranges and rematerializing per step.
    #define PIN(v) asm volatile("" : "+v"(v))
    PIN(BETA); PIN(FC); PIN(K2); PIN(PERCc); PIN(TT); PIN(CFMAX); PIN(CWH);
    PIN(invLPFC); PIN(nCFMAX_TT); PIN(nCFRCFMAX); PIN(CFRCFMAX_TT);
    PIN(nBLFC); PIN(OMK0); PIN(K0UZL); PIN(OMK1); PIN(OMK2);
    #undef PIN

    float SP = 0.001f, MW = 0.001f, SM = 0.001f, SUZ = 0.001f, SLZ = 0.001f;

    // 32-bit byte offsets from uniform (SGPR) bases -> saddr-form loads/stores
    const char* xb = (const char*)x;
    char* ob = (char*)out;
    const uint32_t xstep = (uint32_t)G * 12u;                 // bytes per timestep in x
    uint32_t poff = (uint32_t)g * 12u;
    const uint32_t xmax  = poff + (uint32_t)(T - 1) * xstep;  // clamp target (last valid row)
    uint32_t ooff = (uint32_t)tid * 4u;
    const uint32_t ostep = (uint32_t)(G * NM) * 4u;

    // --- rolling forcing buffer; state-independent precompute hoisted into refill ---
    float Rb[PFD], Sb[PFD], MC[PFD], RC[PFD], Eb[PFD], PE[PFD];

    #define REFILL_BODY(d)                                                     \
        const float* a_ = (const float*)(xb + poff);                           \
        const float P_  = a_[0];   /* adjacent dwords -> global_load_dwordx3 */\
        const float Tt_ = a_[1];                                               \
        const float E_  = a_[2];                                               \
        const float r_  = (Tt_ >= TT) ? P_ : 0.0f;                             \
        Rb[d] = r_;                                                            \
        Sb[d] = P_ - r_;                                                       \
        MC[d] = fmaxf(fmaf(CFMAX, Tt_, nCFMAX_TT), 0.0f);                      \
        RC[d] = fmaxf(fmaf(nCFRCFMAX, Tt_, CFRCFMAX_TT), 0.0f);                \
        Eb[d] = E_;                                                            \
        PE[d] = E_ * invLPFC;

    // hot-loop refill: provably in-bounds, no clamp (1 VALU instead of 3)
    #define REFILL_NC(d) { REFILL_BODY(d) poff += xstep; }
    // tail refill: branch-free clamp keeps reads in-bounds
    #define REFILL_CL(d) { REFILL_BODY(d)                                      \
        const uint32_t nx_ = poff + xstep;                                     \
        poff = (nx_ < xmax) ? nx_ : xmax; }

    #pragma unroll
    for (int d = 0; d < PFD; ++d) REFILL_CL(d)

    auto step = [&](float RAIN, float SNOW, float mc, float rc, float PET, float Pe) -> float {
        // --- snow routine (caps pre-clamped at refill) ---
        SP += SNOW;
        const float melt = fminf(mc, SP);
        MW += melt;
        SP -= melt;
        const float refr = fminf(rc, MW);
        SP += refr;
        MW -= refr;
        const float cw = CWH * SP;
        const float ts = fmaxf(MW - cw, 0.0f);
        MW = fminf(MW, cw);                               // == MW - ts

        // --- soil routine ---
        const float lg = __builtin_amdgcn_logf(SM);       // log2(SM); SM >= 1e-5 always
        const float bl = fminf(fmaf(BETA, lg, nBLFC), 0.0f);  // BETA*log2(SM/FC), clamped
        const float sw = __builtin_amdgcn_exp2f(bl);      // == clip((SM/FC)^BETA, 0, 1)
        const float rt = RAIN + ts;
        const float rg = rt * sw;
        SM = SM + rt - rg;
        const float ex = fmaxf(SM - FC, 0.0f);
        SM = fminf(SM, FC);                               // == SM - ex
        const float et = fminf(fminf(SM, SM * Pe), PET);  // min3; Pe = PET/(LP*FC)
        SM = fmaxf(SM - et, 1e-5f);

        // --- response routine (Q0+Q1 == s2 - s4) ---
        SUZ = SUZ + rg + ex;
        const float pc = fminf(SUZ, PERCc);
        const float s2 = fmaxf(SUZ - PERCc, 0.0f);        // == SUZ - pc
        const float s3 = fminf(s2, fmaf(OMK0, s2, K0UZL));// == s2 - K0*max(s2-UZL,0)
        const float s4 = s3 * OMK1;                       // == s3 - Q1
        SUZ = s4;
        const float sl = SLZ + pc;
        const float q2 = K2 * sl;
        SLZ = sl * OMK2;                                  // == sl - q2
        return (s2 - s4) + q2;                            // Q0 + Q1 + Q2
    };

    // --- main loop: refill target tb+d+PFD <= T-1 guaranteed -> clamp-free ---
    int tb = 0;
    for (; tb + 2 * PFD <= T; tb += PFD) {
        #pragma unroll
        for (int d = 0; d < PFD; ++d) {
            const float R = Rb[d], S = Sb[d], mc = MC[d], rc = RC[d], E = Eb[d], Pe = PE[d];
            REFILL_NC(d)                    // loads issue before the dependent step math
            const float Q = step(R, S, mc, rc, E, Pe);
            *(float*)(ob + ooff) = Q;       // 64 consecutive floats per wave: coalesced
            ooff += ostep;
        }
    }
    // --- tail: <= 2*PFD guarded steps with clamped refill ---
    for (; tb < T; tb += PFD) {
        #pragma unroll
        for (int d = 0; d < PFD; ++d) {
            if (tb + d < T) {
                const float R = Rb[d], S = Sb[d], mc = MC[d], rc = RC[d], E = Eb[d], Pe = PE[d];
                REFILL_CL(d)
                const float Q = step(R, S, mc, rc, E, Pe);
                *(float*)(ob + ooff) = Q;
                ooff += ostep;
            }
        }
    }
    #undef REFILL_BODY
    #undef REFILL_NC
    #undef REFILL_CL
}

extern "C" void kernel_launch(void* const* d_in, const int* in_sizes, int n_in,
                              void* d_out, int out_size, void* d_ws, size_t ws_size,
                              hipStream_t stream) {
    const float* x    = (const float*)d_in[0];   // [T, G, 3]
    const float* praw = (const float*)d_in[1];   // [1, G, 12, 8]
    float* out = (float*)d_out;                  // [T, G, 8]

    const int G = in_sizes[1] / (NPAR * NM);     // 4000
    const int T = in_sizes[0] / (3 * G);         // 730

    const int total = G * NM;                    // 32000 threads, 1 chain each
    const int block = 64;
    const int grid = (total + block - 1) / block;
    hbv_kernel<<<grid, block, 0, stream>>>(x, praw, out, G, T);
}

// Round 6
// 93.145 us; speedup vs baseline: 1.6681x; 1.2280x over previous
//
#include <hip/hip_runtime.h>
#include <math.h>
#include <stdint.h>

#define NM 8          // nmul
#define NPAR 12
#define PFD 8         // prefetch depth in timesteps (raw-forcing register buffer)

__global__ __launch_bounds__(64, 1) void hbv_kernel(
    const float* __restrict__ x,      // [T, G, 3]  (prcp, tmean, pet)
    const float* __restrict__ praw,   // [1, G, 12, NM] in [0,1)
    float* __restrict__ out,          // [T, G, NM]
    int G, int T)
{
    const int tid = blockIdx.x * blockDim.x + threadIdx.x;
    const int total = G * NM;                // 1 chain per lane
    if (tid >= total) return;
    const int g = tid >> 3;                  // / NM
    const int m = tid & 7;                   // % NM

    // Parameter bounds: BETA, FC, K0, K1, K2, LP, PERC, UZL, TT, CFMAX, CFR, CWH
    const float lb[NPAR] = {1.0f, 50.0f, 0.05f, 0.01f, 0.001f, 0.2f, 0.0f, 0.0f, -2.5f, 0.5f, 0.0f, 0.0f};
    const float ub[NPAR] = {6.0f, 1000.0f, 0.9f, 0.5f, 0.2f, 1.0f, 10.0f, 100.0f, 2.5f, 10.0f, 0.1f, 0.2f};

    float p[NPAR];
    const float* pr = praw + (size_t)g * (NPAR * NM) + m;
    #pragma unroll
    for (int i = 0; i < NPAR; ++i) p[i] = pr[i * NM] * (ub[i] - lb[i]) + lb[i];

    const float BETA = p[0], FC = p[1], K0 = p[2], K1 = p[3], K2 = p[4], LP = p[5],
                PERCc = p[6], UZL = p[7], TT = p[8], CFMAX = p[9], CFR = p[10], CWH = p[11];

    // --- derived loop-invariants (fma-folded) ---
    const float invLPFC     = 1.0f / (LP * FC);
    const float nCFMAX_TT   = -(CFMAX * TT);
    const float nCFRCFMAX   = -(CFR * CFMAX);
    const float CFRCFMAX_TT = (CFR * CFMAX) * TT;
    const float nBLFC       = -BETA * __builtin_amdgcn_logf(FC);  // -BETA*log2(FC)
    const float OMK0        = 1.0f - K0;
    const float K0UZL       = K0 * UZL;
    const float OMK1        = 1.0f - K1;
    const float OMK2        = 1.0f - K2;

    float SP = 0.001f, MW = 0.001f, SM = 0.001f, SUZ = 0.001f, SLZ = 0.001f;

    // 32-bit byte offsets from uniform (SGPR) bases -> saddr-form loads/stores
    const char* xb = (const char*)x;
    char* ob = (char*)out;
    const uint32_t xstep = (uint32_t)G * 12u;                 // bytes per timestep in x
    uint32_t poff = (uint32_t)g * 12u;
    const uint32_t xmax  = poff + (uint32_t)(T - 1) * xstep;  // clamp target (last valid row)
    uint32_t ooff = (uint32_t)tid * 4u;
    const uint32_t ostep = (uint32_t)(G * NM) * 4u;

    // --- RAW forcing buffer: loads only. A slot's load is first consumed
    //     PFD steps after issue -> vmcnt retired, no stall (T14 split). ---
    float Pb[PFD], Tb[PFD], Eb[PFD];

    #define REFILL(d)                                                          \
    {                                                                          \
        const float* a_ = (const float*)(xb + poff);                           \
        Pb[d] = a_[0];   /* adjacent dwords -> one global_load_dwordx3 */      \
        Tb[d] = a_[1];                                                         \
        Eb[d] = a_[2];                                                         \
        const uint32_t nx_ = poff + xstep;                                     \
        poff = (nx_ < xmax) ? nx_ : xmax;  /* branch-free clamp */             \
    }

    #pragma unroll
    for (int d = 0; d < PFD; ++d) REFILL(d)

    // Full step including the state-independent precompute (rain split, caps):
    // those ops depend only on the PFD-steps-old load, so they act as
    // independent filler the scheduler can slot into the dep-chain stalls.
    auto step = [&](float P, float Tt, float E) -> float {
        // --- precompute (state-independent) ---
        const float RAIN = (Tt >= TT) ? P : 0.0f;
        const float SNOW = P - RAIN;
        const float mc = fmaxf(fmaf(CFMAX, Tt, nCFMAX_TT), 0.0f);      // melt cap
        const float rc = fmaxf(fmaf(nCFRCFMAX, Tt, CFRCFMAX_TT), 0.0f);// refreeze cap
        const float Pe = E * invLPFC;

        // --- snow routine ---
        SP += SNOW;
        const float melt = fminf(mc, SP);
        MW += melt;
        SP -= melt;
        const float refr = fminf(rc, MW);
        SP += refr;
        MW -= refr;
        const float cw = CWH * SP;
        const float ts = fmaxf(MW - cw, 0.0f);
        MW = fminf(MW, cw);                               // == MW - ts

        // --- soil routine ---
        const float lg = __builtin_amdgcn_logf(SM);       // log2(SM); SM >= 1e-5 always
        const float bl = fminf(fmaf(BETA, lg, nBLFC), 0.0f);  // BETA*log2(SM/FC), clamped
        const float sw = __builtin_amdgcn_exp2f(bl);      // == clip((SM/FC)^BETA, 0, 1)
        const float rt = RAIN + ts;
        const float rg = rt * sw;
        SM = SM + rt - rg;
        const float ex = fmaxf(SM - FC, 0.0f);
        SM = fminf(SM, FC);                               // == SM - ex
        const float et = fminf(fminf(SM, SM * Pe), E);    // min3; Pe = PET/(LP*FC)
        SM = fmaxf(SM - et, 1e-5f);

        // --- response routine (Q0+Q1 == s2 - s4) ---
        SUZ = SUZ + rg + ex;
        const float pc = fminf(SUZ, PERCc);
        const float s2 = fmaxf(SUZ - PERCc, 0.0f);        // == SUZ - pc
        const float s3 = fminf(s2, fmaf(OMK0, s2, K0UZL));// == s2 - K0*max(s2-UZL,0)
        const float s4 = s3 * OMK1;                       // == s3 - Q1
        SUZ = s4;
        const float sl = SLZ + pc;
        const float q2 = K2 * sl;
        SLZ = sl * OMK2;                                  // == sl - q2
        return (s2 - s4) + q2;                            // Q0 + Q1 + Q2
    };

    // --- main loop: consume slot d (loaded PFD steps ago), then re-issue its load ---
    int tb = 0;
    for (; tb + PFD <= T; tb += PFD) {
        #pragma unroll
        for (int d = 0; d < PFD; ++d) {
            const float P = Pb[d], Tt = Tb[d], E = Eb[d];
            REFILL(d)                       // pure load issue, no dependent math
            const float Q = step(P, Tt, E);
            *(float*)(ob + ooff) = Q;       // 64 consecutive floats per wave: coalesced
            ooff += ostep;
        }
    }
    // --- tail: 0..PFD-1 guarded steps, static slot indices ---
    #pragma unroll
    for (int d = 0; d < PFD; ++d) {
        if (tb + d < T) {
            const float Q = step(Pb[d], Tb[d], Eb[d]);
            *(float*)(ob + ooff) = Q;
            ooff += ostep;
        }
    }
    #undef REFILL
}

extern "C" void kernel_launch(void* const* d_in, const int* in_sizes, int n_in,
                              void* d_out, int out_size, void* d_ws, size_t ws_size,
                              hipStream_t stream) {
    const float* x    = (const float*)d_in[0];   // [T, G, 3]
    const float* praw = (const float*)d_in[1];   // [1, G, 12, 8]
    float* out = (float*)d_out;                  // [T, G, 8]

    const int G = in_sizes[1] / (NPAR * NM);     // 4000
    const int T = in_sizes[0] / (3 * G);         // 730

    const int total = G * NM;                    // 32000 threads, 1 chain each
    const int block = 64;
    const int grid = (total + block - 1) / block;
    hbv_kernel<<<grid, block, 0, stream>>>(x, praw, out, G, T);
}

// Round 7
// 85.378 us; speedup vs baseline: 1.8199x; 1.0910x over previous
//
#include <hip/hip_runtime.h>
#include <math.h>
#include <stdint.h>

#define NM 8          // nmul
#define NPAR 12
#define TCH 128       // timesteps per LDS chunk
#define CHDW (TCH*24) // dwords per chunk buffer (24 dwords = 96B per step-row)
#define NLL 12        // 1KB global_load_lds ops per chunk (TCH*96/1024)

typedef __attribute__((address_space(1))) const void gv_t;
typedef __attribute__((address_space(3))) void lv_t;

__global__ __launch_bounds__(64, 1) void hbv_kernel(
    const float* __restrict__ x,      // [T, G, 3]  (prcp, tmean, pet)
    const float* __restrict__ praw,   // [1, G, 12, NM] in [0,1)
    float* __restrict__ out,          // [T, G, NM]
    int G, int T)
{
    __shared__ float lds[2][CHDW];    // 24,576 B double-buffered forcing stage

    const int lane = threadIdx.x;     // block = 1 wave = 8 g's x 8 m's
    const int b    = blockIdx.x;
    const int g0   = b << 3;
    const int gl   = lane >> 3;       // g within block
    const int m    = lane & 7;
    const int g    = g0 + gl;

    // Parameter bounds: BETA, FC, K0, K1, K2, LP, PERC, UZL, TT, CFMAX, CFR, CWH
    const float lb[NPAR] = {1.0f, 50.0f, 0.05f, 0.01f, 0.001f, 0.2f, 0.0f, 0.0f, -2.5f, 0.5f, 0.0f, 0.0f};
    const float ub[NPAR] = {6.0f, 1000.0f, 0.9f, 0.5f, 0.2f, 1.0f, 10.0f, 100.0f, 2.5f, 10.0f, 0.1f, 0.2f};

    float p[NPAR];
    const float* pr = praw + (size_t)g * (NPAR * NM) + m;
    #pragma unroll
    for (int i = 0; i < NPAR; ++i) p[i] = pr[i * NM] * (ub[i] - lb[i]) + lb[i];

    const float BETA = p[0], FC = p[1], K0 = p[2], K1 = p[3], K2 = p[4], LP = p[5],
                PERCc = p[6], UZL = p[7], TT = p[8], CFMAX = p[9], CFR = p[10], CWH = p[11];

    // --- derived loop-invariants (fma-folded) ---
    const float invLPFC     = 1.0f / (LP * FC);
    const float nCFMAX_TT   = -(CFMAX * TT);
    const float nCFRCFMAX   = -(CFR * CFMAX);
    const float CFRCFMAX_TT = (CFR * CFMAX) * TT;
    const float nBLFC       = -BETA * __builtin_amdgcn_logf(FC);  // -BETA*log2(FC)
    const float OMK0        = 1.0f - K0;
    const float K0UZL       = K0 * UZL;
    const float OMK1        = 1.0f - K1;
    const float OMK2        = 1.0f - K2;

    float SP = 0.001f, MW = 0.001f, SM = 0.001f, SUZ = 0.001f, SLZ = 0.001f;

    // --- chunk-copy geometry (all 16B-aligned: 96 = 6*16, G*12 = 16*3000) ---
    const char* xb = (const char*)x;
    const uint32_t xstep  = (uint32_t)G * 12u;     // bytes per timestep row of x
    const uint32_t gbase  = (uint32_t)g0 * 12u;    // block's column base (16B-aligned)
    const uint32_t lin    = (uint32_t)lane * 16u;  // lane's slice of each 1KB segment
    const uint32_t r0     = lin / 96u;             // row within chunk for segment 0
    const uint32_t c0     = lin % 96u;             // col (byte) within row, in {0,16,..,80}
    const uint32_t rowmax = (uint32_t)(T - 1);

    // Issue one chunk's 12 async 1KB copies HBM -> LDS (no VGPRs held, cannot
    // be sunk by the allocator). LDS dest is wave-uniform base + lane*16,
    // global src is the matching per-lane address; rows clamp to T-1.
    #define ISSUE_CHUNK(cs_, nb_)                                              \
    {                                                                          \
        uint32_t row_ = (uint32_t)(cs_) + r0;                                  \
        uint32_t col_ = c0;                                                    \
        _Pragma("unroll")                                                      \
        for (int i_ = 0; i_ < NLL; ++i_) {                                     \
            const uint32_t rg_ = row_ < rowmax ? row_ : rowmax;                \
            const uint32_t go_ = rg_ * xstep + gbase + col_;                   \
            __builtin_amdgcn_global_load_lds((gv_t*)(xb + go_),                \
                (lv_t*)&lds[nb_][i_ * 256], 16, 0, 0);                         \
            /* advance 1024B = 10 rows + 64B within the 96B-row raster */      \
            row_ += 10u + (col_ >= 32u ? 1u : 0u);                             \
            col_  = (col_ >= 32u) ? (col_ - 32u) : (col_ + 64u);               \
        }                                                                      \
    }

    auto step = [&](float P, float Tt, float E) -> float {
        // --- precompute (state-independent filler for the dep-chain stalls) ---
        const float RAIN = (Tt >= TT) ? P : 0.0f;
        const float SNOW = P - RAIN;
        const float mc = fmaxf(fmaf(CFMAX, Tt, nCFMAX_TT), 0.0f);      // melt cap
        const float rc = fmaxf(fmaf(nCFRCFMAX, Tt, CFRCFMAX_TT), 0.0f);// refreeze cap
        const float Pe = E * invLPFC;

        // --- snow routine ---
        SP += SNOW;
        const float melt = fminf(mc, SP);
        MW += melt;
        SP -= melt;
        const float refr = fminf(rc, MW);
        SP += refr;
        MW -= refr;
        const float cw = CWH * SP;
        const float ts = fmaxf(MW - cw, 0.0f);
        MW = fminf(MW, cw);                               // == MW - ts

        // --- soil routine ---
        const float lg = __builtin_amdgcn_logf(SM);       // log2(SM); SM >= 1e-5
        const float bl = fminf(fmaf(BETA, lg, nBLFC), 0.0f);  // BETA*log2(SM/FC), clamped
        const float sw = __builtin_amdgcn_exp2f(bl);      // == clip((SM/FC)^BETA, 0, 1)
        const float rt = RAIN + ts;
        const float rg = rt * sw;
        SM = SM + rt - rg;
        const float ex = fmaxf(SM - FC, 0.0f);
        SM = fminf(SM, FC);                               // == SM - ex
        const float et = fminf(fminf(SM, SM * Pe), E);    // min3; Pe = PET/(LP*FC)
        SM = fmaxf(SM - et, 1e-5f);

        // --- response routine (Q0+Q1 == s2 - s4) ---
        SUZ = SUZ + rg + ex;
        const float pc = fminf(SUZ, PERCc);
        const float s2 = fmaxf(SUZ - PERCc, 0.0f);        // == SUZ - pc
        const float s3 = fminf(s2, fmaf(OMK0, s2, K0UZL));// == s2 - K0*max(s2-UZL,0)
        const float s4 = s3 * OMK1;                       // == s3 - Q1
        SUZ = s4;
        const float sl = SLZ + pc;
        const float q2 = K2 * sl;
        SLZ = sl * OMK2;                                  // == sl - q2
        return (s2 - s4) + q2;                            // Q0 + Q1 + Q2
    };

    // --- pipeline: buf[c&1] computed while buf[(c+1)&1] streams in ---
    ISSUE_CHUNK(0, 0)

    char* ob = (char*)out;
    uint32_t ooff = (uint32_t)(g * NM + m) * 4u;
    const uint32_t ostep = (uint32_t)(G * NM) * 4u;

    int c = 0;
    for (int cs = 0; cs < T; cs += TCH, ++c) {
        const int nb = c & 1;
        if (cs + TCH < T) {
            ISSUE_CHUNK(cs + TCH, nb ^ 1)
            // newest 12 outstanding VMEM = next chunk's copies; waiting to <=12
            // guarantees THIS chunk's copies (and older stores) retired.
            asm volatile("s_waitcnt vmcnt(12)" ::: "memory");
        } else {
            asm volatile("s_waitcnt vmcnt(0)" ::: "memory");
        }

        const int tcnt = (T - cs < TCH) ? (T - cs) : TCH;
        const float* L = &lds[nb][gl * 3];   // 12B/step; offsets {0,3..21}%32: conflict-free
        #pragma unroll 8
        for (int tt = 0; tt < tcnt; ++tt) {
            const float P = L[0], Tt = L[1], E = L[2];
            L += 24;
            const float Q = step(P, Tt, E);
            *(float*)(ob + ooff) = Q;        // 64 consecutive floats/wave: coalesced
            ooff += ostep;
        }
    }
    #undef ISSUE_CHUNK
}

extern "C" void kernel_launch(void* const* d_in, const int* in_sizes, int n_in,
                              void* d_out, int out_size, void* d_ws, size_t ws_size,
                              hipStream_t stream) {
    const float* x    = (const float*)d_in[0];   // [T, G, 3]
    const float* praw = (const float*)d_in[1];   // [1, G, 12, 8]
    float* out = (float*)d_out;                  // [T, G, 8]

    const int G = in_sizes[1] / (NPAR * NM);     // 4000
    const int T = in_sizes[0] / (3 * G);         // 730

    const int grid = G / 8;                      // 500 single-wave blocks (G % 8 == 0)
    hbv_kernel<<<grid, 64, 0, stream>>>(x, praw, out, G, T);
}